// Round 4
// baseline (188.524 us; speedup 1.0000x reference)
//
#include <hip/hip_runtime.h>

// Problem shapes (fixed by reference setup_inputs)
#define B_DIM 1024
#define C_DIM 128
#define K_DIM 1024
#define E_DIM 4
#define EMBED_ELEMS (B_DIM * C_DIM * E_DIM)

// One block = 4 waves, all on the same c; each wave owns 8 b-rows
// (processed as 2 groups of 4 for register pressure).
// Grid = C * (B/32) = 4096 blocks.
__global__ __launch_bounds__(256) void vqvae_kernel(
    const float* __restrict__ cw_q,      // (B, C*E) f32
    const float* __restrict__ codebook,  // (C, K, E) f32
    float* __restrict__ out)             // [embed | one_hot] f32
{
    __shared__ float4 lds_cb[K_DIM];     // 16 KB: codebook[c], shared by 4 waves

    const int lane = threadIdx.x & 63;
    const int wave = threadIdx.x >> 6;
    const int bid  = blockIdx.x;
    const int c      = bid >> 5;         // 32 blocks per c
    const int btile  = bid & 31;
    const int b_base = btile * 32 + wave * 8;

    const float4* cb4 = (const float4*)codebook + (size_t)c * K_DIM;
    const float4* x4  = (const float4*)cw_q;    // (B, C) float4
    float4* emb4 = (float4*)out;                // (B, C) float4
    float*  oh   = out + EMBED_ELEMS;

    // Cooperative stage of this c's codebook into LDS (coalesced dwordx4).
    for (int t = threadIdx.x; t < K_DIM; t += 256)
        lds_cb[t] = cb4[t];
    __syncthreads();

    // Per-lane ||b_k||^2 in f64 for k = j*64+lane (products of f32 values are
    // exact in f64; argmin ordering == true ordering to ~1e-15).
    double bsq[16];
#pragma unroll
    for (int j = 0; j < 16; ++j) {
        const float4 cb = lds_cb[j * 64 + lane];
        const double bx = (double)cb.x, by = (double)cb.y,
                     bz = (double)cb.z, bw = (double)cb.w;
        bsq[j] = bx * bx + by * by + bz * bz + bw * bw;
    }

    for (int g = 0; g < 2; ++g) {
        // Load 4 rows' x and premultiply by -2 in f64 (exact).
        double x2[4][4];
#pragma unroll
        for (int ii = 0; ii < 4; ++ii) {
            const int b = b_base + g * 4 + ii;
            const float4 x = x4[(size_t)b * C_DIM + c];
            x2[ii][0] = -2.0 * (double)x.x;
            x2[ii][1] = -2.0 * (double)x.y;
            x2[ii][2] = -2.0 * (double)x.z;
            x2[ii][3] = -2.0 * (double)x.w;
        }

        double bestd[4];
        int    bestk[4];
#pragma unroll
        for (int ii = 0; ii < 4; ++ii) { bestd[ii] = INFINITY; bestk[ii] = 0x7fffffff; }

        // Main loop: j outer, 4 rows inner. d' = bsq - 2*dot  (x_sq dropped:
        // constant over k, argmin-invariant). 4 f64 FMA per (row, j).
        for (int j = 0; j < 16; ++j) {
            const float4 cb = lds_cb[j * 64 + lane];
            const double bx = (double)cb.x, by = (double)cb.y,
                         bz = (double)cb.z, bw = (double)cb.w;
            const int k = j * 64 + lane;
#pragma unroll
            for (int ii = 0; ii < 4; ++ii) {
                const double d = fma(bw, x2[ii][3],
                                 fma(bz, x2[ii][2],
                                 fma(by, x2[ii][1],
                                 fma(bx, x2[ii][0], bsq[j]))));
                if (d < bestd[ii]) { bestd[ii] = d; bestk[ii] = k; }  // lowest k wins ties
            }
        }

        // Wave argmin, 4 rows interleaved so shuffle latencies overlap.
#pragma unroll
        for (int off = 32; off >= 1; off >>= 1) {
#pragma unroll
            for (int ii = 0; ii < 4; ++ii) {
                const double od = __shfl_xor(bestd[ii], off);
                const int    oi = __shfl_xor(bestk[ii], off);
                if (od < bestd[ii] || (od == bestd[ii] && oi < bestk[ii])) {
                    bestd[ii] = od; bestk[ii] = oi;
                }
            }
        }

        // Emit this group's outputs (stores spread across kernel lifetime).
#pragma unroll
        for (int ii = 0; ii < 4; ++ii) {
            const int b  = b_base + g * 4 + ii;
            const int bi = bestk[ii];
            float4* row4 = (float4*)(oh + (size_t)(b * C_DIM + c) * K_DIM);
#pragma unroll
            for (int it = 0; it < 4; ++it) {
                const int f  = it * 64 + lane;
                const int k0 = f * 4;
                float4 v;
                v.x = (k0 + 0 == bi) ? 1.0f : 0.0f;
                v.y = (k0 + 1 == bi) ? 1.0f : 0.0f;
                v.z = (k0 + 2 == bi) ? 1.0f : 0.0f;
                v.w = (k0 + 3 == bi) ? 1.0f : 0.0f;
                row4[f] = v;
            }
            if (lane == 0) {
                emb4[(size_t)b * C_DIM + c] = lds_cb[bi];  // gather from LDS
            }
        }
    }
}

extern "C" void kernel_launch(void* const* d_in, const int* in_sizes, int n_in,
                              void* d_out, int out_size, void* d_ws, size_t ws_size,
                              hipStream_t stream) {
    const float* cw_q     = (const float*)d_in[0];
    const float* codebook = (const float*)d_in[1];
    float* out = (float*)d_out;

    const int blocks = C_DIM * (B_DIM / 32);  // 4096
    vqvae_kernel<<<blocks, 256, 0, stream>>>(cw_q, codebook, out);
}